// Round 9
// baseline (238.631 us; speedup 1.0000x reference)
//
#include <hip/hip_runtime.h>
#include <stdint.h>

#define B_ 8
#define H_ 128
#define W_ 128
#define D_ 128
#define N_ (H_*W_)
#define M_ (B_*N_)

typedef __attribute__((ext_vector_type(8))) short short8;
typedef __attribute__((ext_vector_type(4))) float floatx4;

typedef const __attribute__((address_space(1))) void* gas_t;
typedef __attribute__((address_space(3))) void* las_t;

__device__ inline unsigned short f2bf(float f){
  union { float f; unsigned int i; } c; c.f = f;
  unsigned int x = c.i;
  x += 0x7FFF + ((x >> 16) & 1);   // RNE
  return (unsigned short)(x >> 16);
}
__device__ inline float bflo(unsigned int u){
  union { unsigned int i; float f; } c; c.i = u << 16; return c.f;
}
__device__ inline float bfhi(unsigned int u){
  union { unsigned int i; float f; } c; c.i = u & 0xFFFF0000u; return c.f;
}

// ---------------- kernel 0: W -> W^T bf16 ----------------
__global__ void wtrans_kernel(const float* __restrict__ Wq, const float* __restrict__ Wk,
                              const float* __restrict__ Wv, unsigned short* __restrict__ Wt){
  const float* src = blockIdx.x == 0 ? Wq : (blockIdx.x == 1 ? Wk : Wv);
  unsigned short* dst = Wt + blockIdx.x * (D_*D_);
  const int i = blockIdx.y * 256 + threadIdx.x;
  const int k = i >> 7, n = i & 127;
  dst[n*D_ + k] = f2bf(src[i]);
}

// ---------------- kernel 1: FULLY FUSED qkv-projection + 3x3 window attention ----
// (Round-9 resubmit of round-8 kernel: round-8 bench died with an infra error
// before producing any signal; re-audit found no hang/fault mechanism —
// uniform barriers, in-bounds LDS/global accesses, verified swizzle pairs,
// DMA/reader ordering via syncthreads drains. Logic unchanged.)
// V-linearity: out = (Sum_i P_i x(n_i)) @ Wv + (Sum_{in-bounds} P_i) * bv  —
// V never materialized; Q/K/V never touch HBM (rounds 2-7: qkv kernel pinned
// at 57-62us across 6 structures; traffic+stage elimination is the only
// robust lever). One block = 16x16 pixel tile, 512 threads (8 waves).
// LDS: W-stage [0,16384) ushorts (32KB, Wq->Wk->Wv time-multiplexed) |
//      KQY [16384,65536): 384 rows x 128 bf16 (Q tile, then K halo 18x18=324
//      rows (+pad), then y tile; sP overlays rows 380.. as float[256]).
__global__ __launch_bounds__(512, 2) void fused_kernel(
    const float* __restrict__ x, const unsigned short* __restrict__ Wt,
    const float* __restrict__ bq, const float* __restrict__ bk, const float* __restrict__ bv,
    float* __restrict__ out)
{
  __shared__ unsigned short lds[65536];   // 128 KB

  const int u = threadIdx.x;
  const int wave = u >> 6, lane = u & 63, m0 = lane & 15, quad = lane >> 4;
  const int tile = blockIdx.x;            // img*64 + ty*8 + tx
  const int img = tile >> 6, ty = (tile >> 3) & 7, tx = tile & 7;
  const int h0 = ty*16, w0 = tx*16;
  const float* xi = x + (size_t)img * N_ * D_;
  float* outp = out + (size_t)img * N_ * D_;
  const int px = u >> 1, tq = u & 1;      // attention: 2 threads/pixel, 64 dims each
  const int ph = px >> 4, pw = px & 15;
  const float scale = 0.08838834764831845f;

  auto stage_W = [&](int which){
    const unsigned short* Ws = Wt + which*(D_*D_);
    #pragma unroll
    for (int p = 0; p < 4; ++p){
      int s = p*512 + u, n = s >> 4, cp = s & 15, c = cp ^ (n & 7);
      __builtin_amdgcn_global_load_lds((gas_t)(const void*)(Ws + n*128 + c*8),
          (las_t)(void*)((unsigned short*)lds + p*4096 + wave*512), 16, 0, 0);
    }
  };

  // ================= S1: Wq DMA + interior x A-frags (global fp32 -> bf16 regs)
  stage_W(0);
  short8 a[4][2];   // [kk][i]: row = wave*32 + i*16 + m0, k = kk*32 + quad*8 + e
  {
    float4 f[8][2];
    #pragma unroll
    for (int i = 0; i < 2; ++i)
      #pragma unroll
      for (int kk = 0; kk < 4; ++kk){
        const float* gp = xi + (size_t)((h0 + wave*2 + i)*W_ + w0 + m0)*D_ + kk*32 + quad*8;
        f[i*4+kk][0] = *(const float4*)gp;
        f[i*4+kk][1] = *(const float4*)(gp + 4);
      }
    __builtin_amdgcn_sched_barrier(0);   // keep loads batched (rounds 4/6 lesson)
    #pragma unroll
    for (int i = 0; i < 2; ++i)
      #pragma unroll
      for (int kk = 0; kk < 4; ++kk){
        short8 v;
        v[0]=(short)f2bf(f[i*4+kk][0].x); v[1]=(short)f2bf(f[i*4+kk][0].y);
        v[2]=(short)f2bf(f[i*4+kk][0].z); v[3]=(short)f2bf(f[i*4+kk][0].w);
        v[4]=(short)f2bf(f[i*4+kk][1].x); v[5]=(short)f2bf(f[i*4+kk][1].y);
        v[6]=(short)f2bf(f[i*4+kk][1].z); v[7]=(short)f2bf(f[i*4+kk][1].w);
        a[kk][i] = v;
      }
  }
  __syncthreads();   // #1: Wq landed

  // ================= S2: Q-GEMM (M=256) -> Q bf16 to KQY rows 0..255 (swizzled)
  {
    floatx4 acc[8][2] = {};
    #pragma unroll
    for (int kk = 0; kk < 4; ++kk){
      #pragma unroll
      for (int j = 0; j < 8; ++j){
        int n = j*16 + m0;
        int c = (kk*4 + quad) ^ (n & 7);
        short8 b = *(const short8*)&lds[n*128 + c*8];
        #pragma unroll
        for (int i = 0; i < 2; ++i)
          acc[j][i] = __builtin_amdgcn_mfma_f32_16x16x32_bf16(b, a[kk][i], acc[j][i], 0, 0, 0);
      }
    }
    #pragma unroll
    for (int j = 0; j < 8; ++j){
      const float4 bb = *(const float4*)&bq[j*16 + quad*4];
      #pragma unroll
      for (int i = 0; i < 2; ++i){
        int row = wave*32 + i*16 + m0;
        int chunk = j*2 + (quad >> 1);
        uint2 pk;
        pk.x = (unsigned)f2bf(acc[j][i][0]+bb.x) | ((unsigned)f2bf(acc[j][i][1]+bb.y) << 16);
        pk.y = (unsigned)f2bf(acc[j][i][2]+bb.z) | ((unsigned)f2bf(acc[j][i][3]+bb.w) << 16);
        *(uint2*)&lds[16384 + row*128 + ((chunk ^ (row & 7)) << 3) + ((quad & 1) << 2)] = pk;
      }
    }
  }
  __syncthreads();   // #2: Q visible

  // ================= S3: q -> regs (bf16, unpacked later); Wk DMA; halo A-loads
  uint4 qb[8];       // this thread's 64 q dims (bf16 packed), dims [tq*64, tq*64+64)
  #pragma unroll
  for (int c = 0; c < 8; ++c){
    int chunk = tq*8 + c;
    qb[c] = *(const uint4*)&lds[16384 + px*128 + ((chunk ^ (px & 7)) << 3)];
  }
  stage_W(1);        // Wk (W region reads finished at barrier #2)
  short8 ak[4][3];   // halo A-frags: hp = wave*48 + i*16 + m0 (384 rows incl pad)
  {
    int grh[3];
    #pragma unroll
    for (int i = 0; i < 3; ++i){
      int hp = wave*48 + i*16 + m0;
      int hy = hp / 18, hx = hp - hy*18;
      int th = h0 - 1 + hy, tw = w0 - 1 + hx;
      th = min(max(th, 0), 127); tw = min(max(tw, 0), 127);
      grh[i] = th*W_ + tw;     // clamped; garbage K rows masked at score time
    }
    #pragma unroll
    for (int i = 0; i < 3; ++i){
      float4 g[4][2];
      #pragma unroll
      for (int kk = 0; kk < 4; ++kk){
        const float* gp = xi + (size_t)grh[i]*D_ + kk*32 + quad*8;
        g[kk][0] = *(const float4*)gp;
        g[kk][1] = *(const float4*)(gp + 4);
      }
      __builtin_amdgcn_sched_barrier(0);
      #pragma unroll
      for (int kk = 0; kk < 4; ++kk){
        short8 v;
        v[0]=(short)f2bf(g[kk][0].x); v[1]=(short)f2bf(g[kk][0].y);
        v[2]=(short)f2bf(g[kk][0].z); v[3]=(short)f2bf(g[kk][0].w);
        v[4]=(short)f2bf(g[kk][1].x); v[5]=(short)f2bf(g[kk][1].y);
        v[6]=(short)f2bf(g[kk][1].z); v[7]=(short)f2bf(g[kk][1].w);
        ak[kk][i] = v;
      }
    }
  }
  __syncthreads();   // #3: q-reads done (K may overwrite Q region), Wk landed

  // ================= S4: K-GEMM (M=384 incl pad) -> K bf16 to KQY rows (swizzled)
  {
    floatx4 acc[8][3] = {};
    #pragma unroll
    for (int kk = 0; kk < 4; ++kk){
      #pragma unroll
      for (int j = 0; j < 8; ++j){
        int n = j*16 + m0;
        int c = (kk*4 + quad) ^ (n & 7);
        short8 b = *(const short8*)&lds[n*128 + c*8];
        #pragma unroll
        for (int i = 0; i < 3; ++i)
          acc[j][i] = __builtin_amdgcn_mfma_f32_16x16x32_bf16(b, ak[kk][i], acc[j][i], 0, 0, 0);
      }
    }
    #pragma unroll
    for (int j = 0; j < 8; ++j){
      const float4 bb = *(const float4*)&bk[j*16 + quad*4];
      #pragma unroll
      for (int i = 0; i < 3; ++i){
        int row = wave*48 + i*16 + m0;
        int chunk = j*2 + (quad >> 1);
        uint2 pk;
        pk.x = (unsigned)f2bf(acc[j][i][0]+bb.x) | ((unsigned)f2bf(acc[j][i][1]+bb.y) << 16);
        pk.y = (unsigned)f2bf(acc[j][i][2]+bb.z) | ((unsigned)f2bf(acc[j][i][3]+bb.w) << 16);
        *(uint2*)&lds[16384 + row*128 + ((chunk ^ (row & 7)) << 3) + ((quad & 1) << 2)] = pk;
      }
    }
  }
  __syncthreads();   // #4: K visible

  // ================= S6a: Wv DMA (Wk dead) + scores + softmax + y-gather
  stage_W(2);
  float qf[64];
  #pragma unroll
  for (int c = 0; c < 8; ++c){
    unsigned uu[4] = {qb[c].x, qb[c].y, qb[c].z, qb[c].w};
    #pragma unroll
    for (int e = 0; e < 4; ++e){
      qf[c*8 + e*2]     = bflo(uu[e]) * scale;
      qf[c*8 + e*2 + 1] = bfhi(uu[e]) * scale;
    }
  }
  float pim[9]; int gr9[9];
  {
    float s[9];
    #pragma unroll
    for (int i9 = 0; i9 < 9; ++i9){
      const int di = i9/3 - 1, dj = i9%3 - 1;
      const int hidx = (ph + 1 + di)*18 + (pw + 1 + dj);      // always in [0,324)
      float acc = 0.f;
      #pragma unroll
      for (int c = 0; c < 8; ++c){
        int chunk = tq*8 + c;
        uint4 kv = *(const uint4*)&lds[16384 + hidx*128 + ((chunk ^ (hidx & 7)) << 3)];
        unsigned uu[4] = {kv.x, kv.y, kv.z, kv.w};
        #pragma unroll
        for (int e = 0; e < 4; ++e){
          acc += qf[c*8 + e*2]     * bflo(uu[e]);
          acc += qf[c*8 + e*2 + 1] * bfhi(uu[e]);
        }
      }
      acc += __shfl_xor(acc, 1, 64);   // combine the pixel's two threads
      const int th = h0 + ph + di, tw = w0 + pw + dj;
      const bool ok = ((unsigned)th < 128u) && ((unsigned)tw < 128u);
      s[i9] = ok ? acc : 0.f;          // zero-pad semantics: OOB score exactly 0
      const int ch = min(max(th, 0), 127), cw = min(max(tw, 0), 127);
      gr9[i9] = ch*W_ + cw;
      pim[i9] = ok ? 1.f : 0.f;        // mask, applied to P below
    }
    float mx = s[0];
    #pragma unroll
    for (int i9 = 1; i9 < 9; ++i9) mx = fmaxf(mx, s[i9]);
    float l = 0.f;
    #pragma unroll
    for (int i9 = 0; i9 < 9; ++i9){ float e = __expf(s[i9] - mx); s[i9] = e; l += e; }
    const float inv = 1.f / l;
    #pragma unroll
    for (int i9 = 0; i9 < 9; ++i9) pim[i9] *= s[i9] * inv;   // masked P_i
  }
  float sps = 0.f;
  #pragma unroll
  for (int i9 = 0; i9 < 9; ++i9) sps += pim[i9];             // Sum_{in-bounds} P_i
  float y[64];
  #pragma unroll
  for (int d = 0; d < 64; ++d) y[d] = 0.f;
  #pragma unroll
  for (int i9 = 0; i9 < 9; ++i9){
    const float pi = pim[i9];
    const float* gp = xi + (size_t)gr9[i9]*D_ + tq*64;       // x fp32, L2-hot
    #pragma unroll
    for (int c2 = 0; c2 < 16; ++c2){
      float4 xv = *(const float4*)(gp + c2*4);
      y[c2*4+0] += pi*xv.x; y[c2*4+1] += pi*xv.y;
      y[c2*4+2] += pi*xv.z; y[c2*4+3] += pi*xv.w;
    }
  }
  __syncthreads();   // #5: all K-reads done (y may overwrite), Wv landed

  // ================= S6b: y bf16 -> KQY rows 0..255 (swizzled) + sP
  #pragma unroll
  for (int c = 0; c < 8; ++c){
    uint4 pk;
    pk.x = (unsigned)f2bf(y[c*8+0]) | ((unsigned)f2bf(y[c*8+1]) << 16);
    pk.y = (unsigned)f2bf(y[c*8+2]) | ((unsigned)f2bf(y[c*8+3]) << 16);
    pk.z = (unsigned)f2bf(y[c*8+4]) | ((unsigned)f2bf(y[c*8+5]) << 16);
    pk.w = (unsigned)f2bf(y[c*8+6]) | ((unsigned)f2bf(y[c*8+7]) << 16);
    int chunk = tq*8 + c;
    *(uint4*)&lds[16384 + px*128 + ((chunk ^ (px & 7)) << 3)] = pk;
  }
  {
    float* sPw = (float*)&lds[16384 + 380*128];   // overlays dead K pad rows
    if (tq == 0) sPw[px] = sps;
  }
  __syncthreads();   // #6: y + sP visible

  // ================= S7: out-GEMM (y @ Wv) + sP*bv epilogue, fp32 stores
  {
    short8 ay[4][2];
    #pragma unroll
    for (int kk = 0; kk < 4; ++kk)
      #pragma unroll
      for (int i = 0; i < 2; ++i){
        int row = wave*32 + i*16 + m0;
        int c = (kk*4 + quad) ^ (row & 7);
        ay[kk][i] = *(const short8*)&lds[16384 + row*128 + c*8];
      }
    floatx4 acc[8][2] = {};
    #pragma unroll
    for (int kk = 0; kk < 4; ++kk){
      #pragma unroll
      for (int j = 0; j < 8; ++j){
        int n = j*16 + m0;
        int c = (kk*4 + quad) ^ (n & 7);
        short8 b = *(const short8*)&lds[n*128 + c*8];
        #pragma unroll
        for (int i = 0; i < 2; ++i)
          acc[j][i] = __builtin_amdgcn_mfma_f32_16x16x32_bf16(b, ay[kk][i], acc[j][i], 0, 0, 0);
      }
    }
    const float* sPr = (const float*)&lds[16384 + 380*128];
    #pragma unroll
    for (int j = 0; j < 8; ++j){
      const float4 bb = *(const float4*)&bv[j*16 + quad*4];
      #pragma unroll
      for (int i = 0; i < 2; ++i){
        int row = wave*32 + i*16 + m0;
        float sp = sPr[row];
        int gr = (h0 + wave*2 + i)*W_ + w0 + m0;
        float4 v = make_float4(acc[j][i][0] + sp*bb.x, acc[j][i][1] + sp*bb.y,
                               acc[j][i][2] + sp*bb.z, acc[j][i][3] + sp*bb.w);
        *(float4*)(outp + (size_t)gr*D_ + j*16 + quad*4) = v;
      }
    }
  }
}

extern "C" void kernel_launch(void* const* d_in, const int* in_sizes, int n_in,
                              void* d_out, int out_size, void* d_ws, size_t ws_size,
                              hipStream_t stream)
{
  const float* x  = (const float*)d_in[0];
  const float* Wq = (const float*)d_in[1];
  const float* bq = (const float*)d_in[2];
  const float* Wk = (const float*)d_in[3];
  const float* bk = (const float*)d_in[4];
  const float* Wv = (const float*)d_in[5];
  const float* bv = (const float*)d_in[6];
  float* out = (float*)d_out;

  unsigned short* Wt = (unsigned short*)d_ws;   // 96 KB only — Q/K/V never materialized

  hipLaunchKernelGGL(wtrans_kernel, dim3(3, 64), dim3(256), 0, stream, Wq, Wk, Wv, Wt);
  hipLaunchKernelGGL(fused_kernel, dim3(512), dim3(512), 0, stream,
                     x, Wt, bq, bk, bv, out);
}

// Round 10
// 184.762 us; speedup vs baseline: 1.2916x; 1.2916x over previous
//
#include <hip/hip_runtime.h>
#include <stdint.h>

#define B_ 8
#define H_ 128
#define W_ 128
#define D_ 128
#define N_ (H_*W_)
#define M_ (B_*N_)   // 131072 rows total

typedef __attribute__((ext_vector_type(8))) short short8;
typedef __attribute__((ext_vector_type(4))) float floatx4;

typedef const __attribute__((address_space(1))) void* gas_t;
typedef __attribute__((address_space(3))) void* las_t;

__device__ inline unsigned short f2bf(float f){
  union { float f; unsigned int i; } c; c.f = f;
  unsigned int x = c.i;
  x += 0x7FFF + ((x >> 16) & 1);   // RNE
  return (unsigned short)(x >> 16);
}
__device__ inline float bflo(unsigned int u){
  union { unsigned int i; float f; } c; c.i = u << 16; return c.f;
}
__device__ inline float bfhi(unsigned int u){
  union { unsigned int i; float f; } c; c.i = u & 0xFFFF0000u; return c.f;
}

// ---------------- kernel 0: W -> W^T bf16 ----------------
__global__ void wtrans_kernel(const float* __restrict__ Wq, const float* __restrict__ Wk,
                              const float* __restrict__ Wv, unsigned short* __restrict__ Wt){
  const float* src = blockIdx.x == 0 ? Wq : (blockIdx.x == 1 ? Wk : Wv);
  unsigned short* dst = Wt + blockIdx.x * (D_*D_);
  const int i = blockIdx.y * 256 + threadIdx.x;
  const int k = i >> 7, n = i & 127;
  dst[n*D_ + k] = f2bf(src[i]);
}

// ---------------- kernel 1: FUSED QKV projection (round-2 version, verbatim) ----
// Best of 7 measured qkv structures (56.1-57.6 us). One block = 128-row tile,
// x read ONCE; B restaged per which via global_load_lds; LDS epilogue w/ +8 pad.
__global__ __launch_bounds__(256, 2) void qkv_gemm_kernel(
    const float* __restrict__ x, const unsigned short* __restrict__ Wt,
    const float* __restrict__ bq, const float* __restrict__ bk, const float* __restrict__ bv,
    unsigned short* __restrict__ Q, unsigned short* __restrict__ K, unsigned short* __restrict__ V)
{
  const int rowTile = blockIdx.x;

  __shared__ unsigned short lds[32768];  // 64 KB -> 2 blocks/CU

  const int t = threadIdx.x;
  const int wave = t >> 6, lane = t & 63;

  // ---- A stage (once): fp32 x -> bf16, swizzled ds_write_b128
  {
    const float* xrow = x + (size_t)rowTile * 128 * D_;
    #pragma unroll
    for (int p = 0; p < 8; ++p){
      int s = p*256 + t;
      int r = s >> 4, cp = s & 15, c = cp ^ (r & 7);
      const float* gp = xrow + r*D_ + c*8;
      float4 f0 = *(const float4*)gp;
      float4 f1 = *(const float4*)(gp + 4);
      uint4 pk;
      pk.x = (unsigned)f2bf(f0.x) | ((unsigned)f2bf(f0.y) << 16);
      pk.y = (unsigned)f2bf(f0.z) | ((unsigned)f2bf(f0.w) << 16);
      pk.z = (unsigned)f2bf(f1.x) | ((unsigned)f2bf(f1.y) << 16);
      pk.w = (unsigned)f2bf(f1.z) | ((unsigned)f2bf(f1.w) << 16);
      *(uint4*)&lds[s*8] = pk;
    }
  }

  const int wm = (wave >> 1) * 64, wn = (wave & 1) * 64;
  const int m0 = lane & 15, quad = lane >> 4;

  #pragma unroll
  for (int which = 0; which < 3; ++which){
    const float* bias = which == 0 ? bq : (which == 1 ? bk : bv);
    unsigned short* Out = which == 0 ? Q : (which == 1 ? K : V);
    const unsigned short* Wsel = Wt + which * (D_*D_);

    // ---- B stage: async global->LDS, 16B/lane
    #pragma unroll
    for (int p = 0; p < 8; ++p){
      int s = p*256 + t;                 // 16B chunk id
      int n = s >> 4, cp = s & 15, c = cp ^ (n & 7);
      const unsigned short* gp = Wsel + n*128 + c*8;
      unsigned short* lp = (unsigned short*)lds + 16384 + p*2048 + wave*512;
      __builtin_amdgcn_global_load_lds((gas_t)(const void*)gp, (las_t)(void*)lp, 16, 0, 0);
    }
    __syncthreads();

    floatx4 acc[4][4] = {};
    #pragma unroll
    for (int kk = 0; kk < 4; ++kk){
      short8 a[4], b[4];
      #pragma unroll
      for (int i = 0; i < 4; ++i){
        int row = wm + i*16 + m0;
        int c = (kk*4 + quad) ^ (row & 7);
        a[i] = *(const short8*)&lds[row*128 + c*8];
      }
      #pragma unroll
      for (int j = 0; j < 4; ++j){
        int n = wn + j*16 + m0;
        int c = (kk*4 + quad) ^ (n & 7);
        b[j] = *(const short8*)&lds[16384 + n*128 + c*8];
      }
      #pragma unroll
      for (int i = 0; i < 4; ++i)
        #pragma unroll
        for (int j = 0; j < 4; ++j)
          acc[i][j] = __builtin_amdgcn_mfma_f32_16x16x32_bf16(a[i], b[j], acc[i][j], 0, 0, 0);
    }

    // ---- epilogue: reuse B region (16384 ushorts) in two 64-row halves
    __syncthreads();   // everyone done reading B
    unsigned short* Outp = Out + (size_t)rowTile * 128 * D_;
    #pragma unroll
    for (int half = 0; half < 2; ++half){
      if ((wave >> 1) == half){          // waves owning rows half*64 .. half*64+63
        #pragma unroll
        for (int j = 0; j < 4; ++j){
          const int col = wn + j*16 + m0;
          const float bb = bias[col];
          #pragma unroll
          for (int i = 0; i < 4; ++i){
            #pragma unroll
            for (int r = 0; r < 4; ++r){
              int lrow = i*16 + quad*4 + r;   // local row within half
              lds[16384 + lrow*136 + col] = f2bf(acc[i][j][r] + bb);
            }
          }
        }
      }
      __syncthreads();
      #pragma unroll
      for (int p = 0; p < 4; ++p){
        int rr = p*16 + (t >> 4), cc = t & 15;
        uint4 vv = *(const uint4*)&lds[16384 + rr*136 + cc*8];
        *(uint4*)(Outp + half*8192 + p*2048 + t*8) = vv;
      }
      __syncthreads();
    }
  }
}

// ---------------- kernel 2: 3x3 window attention, 16 threads/pixel ----------------
// 8 dims/thread -> ku[9]+vu[9] = 72 payload VGPR, peak live ~90 -> fits the
// 128-VGPR cap of launch_bounds(256,4) = 4 waves/SIMD (2x round-2 occupancy).
// Spill-safe: all loads unconditional clamped-address (round-1's spill came
// from control-flow-merged array defs, removed since round 2). Batched issue:
// q -> all 9 K -> scores -> all 9 V (fly under shfl-reduce+softmax) -> PV.
__global__ __launch_bounds__(256, 4) void attn_kernel(
    const unsigned short* __restrict__ Q, const unsigned short* __restrict__ K,
    const unsigned short* __restrict__ V, float* __restrict__ out)
{
  const int t = threadIdx.x;
  const int e16 = t & 15;                    // which 8-dim chunk
  const int pix = blockIdx.x * 16 + (t >> 4);
  const int w = pix & 127;
  const int h = (pix >> 7) & 127;
  const int bbase = pix & ~(N_ - 1);         // first pixel of this batch image
  const float scale = 0.08838834764831845f;  // 1/sqrt(128)
  const int doff = e16 * 8;
  const size_t off = (size_t)pix * D_ + doff;

  // ---- neighbor pixel indices, clamped into the image (always valid)
  int npix[9]; bool okm[9];
  #pragma unroll
  for (int i = 0; i < 9; ++i){
    const int dy = i/3 - 1, dx = i%3 - 1;
    const int hh = h + dy, ww = w + dx;
    okm[i] = ((unsigned)hh < 128u) && ((unsigned)ww < 128u);
    const int hc = min(max(hh, 0), 127);
    const int wc = min(max(ww, 0), 127);
    npix[i] = bbase + hc*W_ + wc;
  }

  // ---- q (1 uint4), then ALL 9 K loads (unconditional -> batchable)
  uint4 qu = *(const uint4*)(Q + off);
  uint4 ku[9];
  #pragma unroll
  for (int i = 0; i < 9; ++i)
    ku[i] = *(const uint4*)(K + (size_t)npix[i]*D_ + doff);

  float q[8];
  {
    unsigned uu[4] = {qu.x, qu.y, qu.z, qu.w};
    #pragma unroll
    for (int e = 0; e < 4; ++e){
      q[e*2]     = bflo(uu[e]) * scale;
      q[e*2 + 1] = bfhi(uu[e]) * scale;
    }
  }

  // ---- partial dot products (8 dims); OOB -> exact 0 via scalar select
  float s[9];
  #pragma unroll
  for (int i = 0; i < 9; ++i){
    unsigned uu[4] = {ku[i].x, ku[i].y, ku[i].z, ku[i].w};
    float acc = 0.f;
    #pragma unroll
    for (int e = 0; e < 4; ++e){
      acc += q[e*2]     * bflo(uu[e]);
      acc += q[e*2 + 1] * bfhi(uu[e]);
    }
    s[i] = okm[i] ? acc : 0.f;
  }

  // ---- issue ALL 9 V loads now; they fly under the reduce + softmax
  uint4 vu[9];
  #pragma unroll
  for (int i = 0; i < 9; ++i)
    vu[i] = *(const uint4*)(V + (size_t)npix[i]*D_ + doff);

  // 16-lane reduce (all 16 lanes of a pixel share okm -> select-then-reduce ok)
  #pragma unroll
  for (int i = 0; i < 9; ++i){
    s[i] += __shfl_xor(s[i], 1, 64);
    s[i] += __shfl_xor(s[i], 2, 64);
    s[i] += __shfl_xor(s[i], 4, 64);
    s[i] += __shfl_xor(s[i], 8, 64);
  }

  // ---- softmax (OOB score is exactly 0, participates — ref zero-pad semantics)
  float m = s[0];
  #pragma unroll
  for (int i = 1; i < 9; ++i) m = fmaxf(m, s[i]);
  float l = 0.f;
  float p[9];
  #pragma unroll
  for (int i = 0; i < 9; ++i){ p[i] = __expf(s[i] - m); l += p[i]; }
  const float inv = 1.f / l;

  // ---- PV accumulate; OOB contributes 0 via select on pi
  float o[8];
  #pragma unroll
  for (int d = 0; d < 8; ++d) o[d] = 0.f;
  #pragma unroll
  for (int i = 0; i < 9; ++i){
    const float pi = okm[i] ? p[i] * inv : 0.f;
    unsigned uu[4] = {vu[i].x, vu[i].y, vu[i].z, vu[i].w};
    #pragma unroll
    for (int e = 0; e < 4; ++e){
      o[e*2]     += pi * bflo(uu[e]);
      o[e*2 + 1] += pi * bfhi(uu[e]);
    }
  }

  float* op = out + off;
  *(float4*)op       = make_float4(o[0], o[1], o[2], o[3]);
  *(float4*)(op + 4) = make_float4(o[4], o[5], o[6], o[7]);
}

extern "C" void kernel_launch(void* const* d_in, const int* in_sizes, int n_in,
                              void* d_out, int out_size, void* d_ws, size_t ws_size,
                              hipStream_t stream)
{
  const float* x  = (const float*)d_in[0];
  const float* Wq = (const float*)d_in[1];
  const float* bq = (const float*)d_in[2];
  const float* Wk = (const float*)d_in[3];
  const float* bk = (const float*)d_in[4];
  const float* Wv = (const float*)d_in[5];
  const float* bv = (const float*)d_in[6];
  float* out = (float*)d_out;

  char* ws = (char*)d_ws;
  unsigned short* Wt = (unsigned short*)ws;                                   // 96 KB
  unsigned short* Q  = (unsigned short*)(ws + (1<<17));
  unsigned short* K  = (unsigned short*)(ws + (1<<17) + (size_t)M_*D_*2);
  unsigned short* V  = (unsigned short*)(ws + (1<<17) + (size_t)2*M_*D_*2);   // ~96.1 MB

  hipLaunchKernelGGL(wtrans_kernel, dim3(3, 64), dim3(256), 0, stream, Wq, Wk, Wv, Wt);
  hipLaunchKernelGGL(qkv_gemm_kernel, dim3(M_/128), dim3(256), 0, stream,
                     x, Wt, bq, bk, bv, Q, K, V);
  hipLaunchKernelGGL(attn_kernel, dim3(M_/16), dim3(256), 0, stream, Q, K, V, out);
}